// Round 1
// 457.857 us; speedup vs baseline: 1.0395x; 1.0395x over previous
//
#include <hip/hip_runtime.h>
#include <cstdint>
#include <math.h>

#define S_LEN 2048
#define BATCH 2
#define HID   2048
#define NHEAD 16
#define DHEAD 128

typedef _Float16 h8 __attribute__((ext_vector_type(8)));
typedef _Float16 h4 __attribute__((ext_vector_type(4)));
typedef float f32x4 __attribute__((ext_vector_type(4)));

// async global->LDS, 16B per lane; LDS dest = wave-uniform base + lane*16
__device__ __forceinline__ void gload16(const void* g, void* l) {
  __builtin_amdgcn_global_load_lds(
      (const __attribute__((address_space(1))) unsigned int*)g,
      (__attribute__((address_space(3))) unsigned int*)l, 16, 0, 0);
}

// ---------------------------------------------------------------------------
// R10: 256x256-tile 8-phase GEMM (T2 swizzle + T3/T4 counted vmcnt + T5
// setprio), plain-HIP port of the m201 template to fp16.
// C[M,N] = A[M,K] @ Bt[N,K]^T (+bias). 512 thr = 8 waves (2M x 4N); each
// wave owns a 128x64 output tile (8x4 frags of 16x16, acc = 32 f32x4).
// BK=64; LDS = 2 dbuf x 2 half x [128][64] fp16 for A and B = 128 KiB.
//
// LDS granule swizzle: logical granule (row, gc) lives at phys granule
// row*8 + (gc ^ (row&7)). global_load_lds writes linearly, so the swizzle
// is applied by permuting the per-lane GLOBAL source address (rule #21:
// both-sides-or-neither); ds_read applies the same XOR. Each frag read
// then hits all 8 granule-columns uniformly (2 lanes/bank = free).
//
// Phase schedule per K-tile u (each phase: {ds_read, stage, barrier,
// lgkmcnt(0), setprio(1) 16xMFMA setprio(0), barrier}):
//   q1: read A-lo(u);  stage A1(u+1)->buf^1 ; MFMA Q11(u-1)  [m4-7 x n2-3]
//   q2: read B all(u);                        MFMA Q00(u)    [m0-3 x n0-1]
//   q3: read A-hi(u);  stage B0,B1(u+2)->buf; MFMA Q10(u)    [m4-7 x n0-1]
//   q4:                stage A0(u+2)->buf; vmcnt(6); MFMA Q01(u)
// Ledger: every slot staged >=1 barrier after its previous tenant's last
// read (A slots last read q3, B slots q2); every read covered by the
// vmcnt(6) of the previous group (3 half-tiles = 6 loads in flight, never
// drained to 0 mid-loop). Epilogue: vmcnt(0) once at u=NT-2.
// ---------------------------------------------------------------------------
template <bool HAS_BIAS, bool OUT_HALF>
__global__ __launch_bounds__(512) void gemm_256(
    const _Float16* __restrict__ A, const _Float16* __restrict__ Bt,
    const float* __restrict__ bias, void* __restrict__ Cout, int M, int N,
    int K) {
  __shared__ _Float16 LA[2][2][8192];
  __shared__ _Float16 LB[2][2][8192];
  const int tid = (int)threadIdx.x;
  const int wave = tid >> 6, lane = tid & 63;
  const int ln = lane & 15, quad = lane >> 4;
  const int wm = wave >> 2, wn = wave & 3;  // 2 x 4 wave grid
  const int bm = (int)blockIdx.y * 256, bn = (int)blockIdx.x * 256;
  const int NT = K >> 6;

  // staging: wave stages chunks {2w,2w+1}; chunk c = phys granules c*64+l
  // lane l sources global (row = c*8 + (l>>3), granule (l&7)^(l>>3))
  const int rA = wave * 16 + (lane >> 3);
  const int gc8 = ((lane & 7) ^ (lane >> 3)) * 8;
  const uint32_t oA00 = (uint32_t)(bm + rA) * (uint32_t)K + (uint32_t)gc8;
  const uint32_t oA01 = oA00 + (uint32_t)(8 * K);
  const uint32_t oA10 = oA00 + (uint32_t)(128 * K);
  const uint32_t oA11 = oA10 + (uint32_t)(8 * K);
  const uint32_t oB00 = (uint32_t)(bn + rA) * (uint32_t)K + (uint32_t)gc8;
  const uint32_t oB01 = oB00 + (uint32_t)(8 * K);
  const uint32_t oB10 = oB00 + (uint32_t)(128 * K);
  const uint32_t oB11 = oB10 + (uint32_t)(8 * K);
  const int cw0 = wave * 1024;  // LDS chunk bases (halves), wave-uniform
  const int cw1 = cw0 + 512;

#define STAGE_A(h_, bb_, u_)                                           \
  {                                                                    \
    gload16(A + (oA##h_##0 + (uint32_t)(u_)*64u), &LA[bb_][h_][cw0]);  \
    gload16(A + (oA##h_##1 + (uint32_t)(u_)*64u), &LA[bb_][h_][cw1]);  \
  }
#define STAGE_B(h_, bb_, u_)                                           \
  {                                                                    \
    gload16(Bt + (oB##h_##0 + (uint32_t)(u_)*64u), &LB[bb_][h_][cw0]); \
    gload16(Bt + (oB##h_##1 + (uint32_t)(u_)*64u), &LB[bb_][h_][cw1]); \
  }

  // ds_read addressing (elements): row*64 + 8*((4*kk+quad)^(ln&7))
  const int arow = ln * 64;
  const int sc0 = ((quad ^ (ln & 7))) * 8;
  const int sc1 = (((4 + quad) ^ (ln & 7))) * 8;
  const int bro = (wn & 1) * 4096;  // wave's row offset within its B half

  f32x4 acc[8][4];
#pragma unroll
  for (int m = 0; m < 8; m++)
#pragma unroll
    for (int n = 0; n < 4; n++) acc[m][n] = (f32x4){0.f, 0.f, 0.f, 0.f};
  h8 aLo[4][2], aHi[4][2], bF[4][2];

#define QUAD(aF_, mo_, no_)                                                  \
  _Pragma("unroll") for (int mm_ = 0; mm_ < 4; mm_++)                        \
      _Pragma("unroll") for (int nn_ = 0; nn_ < 2; nn_++) {                  \
    acc[(mo_) + mm_][(no_) + nn_] = __builtin_amdgcn_mfma_f32_16x16x32_f16(  \
        aF_[mm_][0], bF[(no_) + nn_][0], acc[(mo_) + mm_][(no_) + nn_], 0,   \
        0, 0);                                                               \
    acc[(mo_) + mm_][(no_) + nn_] = __builtin_amdgcn_mfma_f32_16x16x32_f16(  \
        aF_[mm_][1], bF[(no_) + nn_][1], acc[(mo_) + mm_][(no_) + nn_], 0,   \
        0, 0);                                                               \
  }

  // ---- prologue: tile0 (all 4 halves) + A0,B0,B1 of tile1; 3 in flight ----
  STAGE_A(0, 0, 0) STAGE_A(1, 0, 0) STAGE_B(0, 0, 0) STAGE_B(1, 0, 0)
  STAGE_A(0, 1, 1) STAGE_B(0, 1, 1) STAGE_B(1, 1, 1)
  asm volatile("s_waitcnt vmcnt(6)" ::: "memory");
  __builtin_amdgcn_s_barrier();

  for (int u = 0; u < NT; ++u) {
    const int bb = u & 1;

    // ---- q1: read A-lo(u); stage A1(u+1); MFMA Q11(u-1) ----
#pragma unroll
    for (int m = 0; m < 4; m++) {
      aLo[m][0] = *(const h8*)&LA[bb][wm][m * 1024 + arow + sc0];
      aLo[m][1] = *(const h8*)&LA[bb][wm][m * 1024 + arow + sc1];
    }
    if (u + 1 < NT) STAGE_A(1, bb ^ 1, u + 1)
    __builtin_amdgcn_s_barrier();
    asm volatile("s_waitcnt lgkmcnt(0)" ::: "memory");
    if (u) {
      __builtin_amdgcn_s_setprio(1);
      QUAD(aHi, 4, 2)
      __builtin_amdgcn_s_setprio(0);
    }
    __builtin_amdgcn_s_barrier();

    // ---- q2: read B(u) (all 4 n-frags); MFMA Q00(u) ----
#pragma unroll
    for (int n = 0; n < 4; n++) {
      bF[n][0] = *(const h8*)&LB[bb][wn >> 1][bro + n * 1024 + arow + sc0];
      bF[n][1] = *(const h8*)&LB[bb][wn >> 1][bro + n * 1024 + arow + sc1];
    }
    __builtin_amdgcn_s_barrier();
    asm volatile("s_waitcnt lgkmcnt(0)" ::: "memory");
    __builtin_amdgcn_s_setprio(1);
    QUAD(aLo, 0, 0)
    __builtin_amdgcn_s_setprio(0);
    __builtin_amdgcn_s_barrier();

    // ---- q3: read A-hi(u); stage B0,B1(u+2); MFMA Q10(u) ----
#pragma unroll
    for (int m = 0; m < 4; m++) {
      aHi[m][0] = *(const h8*)&LA[bb][wm][(m + 4) * 1024 + arow + sc0];
      aHi[m][1] = *(const h8*)&LA[bb][wm][(m + 4) * 1024 + arow + sc1];
    }
    if (u + 2 < NT) { STAGE_B(0, bb, u + 2) STAGE_B(1, bb, u + 2) }
    __builtin_amdgcn_s_barrier();
    asm volatile("s_waitcnt lgkmcnt(0)" ::: "memory");
    __builtin_amdgcn_s_setprio(1);
    QUAD(aHi, 4, 0)
    __builtin_amdgcn_s_setprio(0);
    __builtin_amdgcn_s_barrier();

    // ---- q4: stage A0(u+2); counted vmcnt; MFMA Q01(u) ----
    if (u + 2 < NT) {
      STAGE_A(0, bb, u + 2)
      asm volatile("s_waitcnt vmcnt(6)" ::: "memory");
    } else if (u + 1 < NT) {
      asm volatile("s_waitcnt vmcnt(0)" ::: "memory");
    }
    __builtin_amdgcn_s_barrier();
    __builtin_amdgcn_s_setprio(1);
    QUAD(aLo, 0, 2)
    __builtin_amdgcn_s_setprio(0);
    __builtin_amdgcn_s_barrier();
  }

  // ---- flush-phase: Q11 of the last tile ----
  __builtin_amdgcn_s_setprio(1);
  QUAD(aHi, 4, 2)
  __builtin_amdgcn_s_setprio(0);
#undef QUAD
#undef STAGE_A
#undef STAGE_B

  // ---- epilogue ----
#pragma unroll
  for (int m = 0; m < 8; m++) {
#pragma unroll
    for (int r = 0; r < 4; r++) {
      const size_t row = (size_t)(bm + wm * 128 + m * 16 + quad * 4 + r);
#pragma unroll
      for (int n = 0; n < 4; n++) {
        const int col = bn + wn * 64 + n * 16 + ln;
        float v = acc[m][n][r];
        if (HAS_BIAS) v += bias[col];
        if (OUT_HALF)
          ((_Float16*)Cout)[row * N + col] = (_Float16)v;
        else
          ((float*)Cout)[row * N + col] = v;
      }
    }
  }
}

__global__ __launch_bounds__(256) void transpose_cvt(
    const float* __restrict__ in, _Float16* __restrict__ out, int K, int N) {
  __shared__ float t[64][65];
  const int bn = blockIdx.x * 64, bk = blockIdx.y * 64;
  const int l = threadIdx.x & 63, g = threadIdx.x >> 6;
#pragma unroll
  for (int i = 0; i < 16; i++) {
    int r = g + 4 * i;
    t[r][l] = in[(size_t)(bk + r) * N + bn + l];
  }
  __syncthreads();
#pragma unroll
  for (int i = 0; i < 16; i++) {
    int r = g + 4 * i;
    out[(size_t)(bn + r) * K + bk + l] = (_Float16)t[l][r];
  }
}

__global__ __launch_bounds__(256) void cvt_fp16(const float* __restrict__ in,
                                                _Float16* __restrict__ out,
                                                int n4) {
  int i = blockIdx.x * blockDim.x + threadIdx.x;
  if (i < n4) {
    float4 v = ((const float4*)in)[i];
    h4 o = {(_Float16)v.x, (_Float16)v.y, (_Float16)v.z, (_Float16)v.w};
    *(h4*)&out[4 * (size_t)i] = o;
  }
}

// ---------------------------------------------------------------------------
// pack_kv (unchanged since R8): K/V of each (z, kt) 32-row tile re-laid into
// MFMA-fragment lane order. Chunk c of a tile is 1 KB contiguous:
//   KP[tile_base + c*512 + lane*8 + j], c = jn*4+kq (K) / c = nt (V).
// This is exactly the wave-uniform-base + lane*16B shape global_load_lds
// needs, so flash staging is a straight async copy.
// ---------------------------------------------------------------------------
__global__ __launch_bounds__(256) void pack_kv(
    const _Float16* __restrict__ mixed, _Float16* __restrict__ KP,
    _Float16* __restrict__ VP) {
  __shared__ _Float16 Tv[128 * 40];
  const int kt = blockIdx.x;
  const int z = blockIdx.y;  // b*NH + h
  const int kb = kt * 32;
  const int tid = threadIdx.x;
  const size_t RS = (size_t)BATCH * NHEAD * 384;
  const _Float16* base = mixed + (size_t)z * 384;

  // Phase A: stage V tile transposed into Tv
  {
    const int r = tid >> 3, d0 = (tid & 7) * 16;
    const _Float16* src = base + (size_t)(kb + r) * RS + 256 + d0;
    h8 v0 = *(const h8*)src;
    h8 v1 = *(const h8*)(src + 8);
#pragma unroll
    for (int e = 0; e < 8; e++) Tv[(d0 + e) * 40 + r] = v0[e];
#pragma unroll
    for (int e = 0; e < 8; e++) Tv[(d0 + 8 + e) * 40 + r] = v1[e];
  }
  __syncthreads();

  const size_t tb = ((size_t)z * 64 + kt) * 8 * 512;
#pragma unroll
  for (int c = 0; c < 2; c++) {
    const int idx = tid + 256 * c;  // 0..511
    const int i = idx >> 6, l = idx & 63;
    const int ln = l & 15, quad = l >> 4;
    {
      const int jn = i >> 2, kq = i & 3;
      h8 v = *(const h8*)(base + (size_t)(kb + 16 * jn + ln) * RS + 128 +
                          32 * kq + 8 * quad);
      *(h8*)&KP[tb + (size_t)i * 512 + l * 8] = v;
    }
    {
      h8 v = *(const h8*)&Tv[(16 * i + ln) * 40 + 8 * quad];
      *(h8*)&VP[tb + (size_t)i * 512 + l * 8] = v;
    }
  }
}

// ---------------------------------------------------------------------------
// fp16-MFMA flash attention v7 (unchanged since R9): LDS double-buffer +
// ONE barrier/tile + async global_load_lds from frag-ordered KP/VP.
// Grid (S/64, NH, B), 256 thr; wave owns 16 q-rows. LDS 37,888 B -> 4
// blocks/CU (16 waves). Reg-Q, no-max softmax, wave-private St.
// ---------------------------------------------------------------------------
__global__ __launch_bounds__(256) void flash_attn_v7(
    const _Float16* __restrict__ mixed, const _Float16* __restrict__ KP,
    const _Float16* __restrict__ VP, const unsigned char* __restrict__ mask,
    _Float16* __restrict__ ctx) {
  const int qt = (int)gridDim.x - 1 - (int)blockIdx.x;  // big blocks first
  const int h = blockIdx.y, b = blockIdx.z;
  const int z = b * NHEAD + h;
  const int qb = qt * 64;
  const int tid = threadIdx.x;
  const int wave = tid >> 6, lane = tid & 63;
  const int ln = lane & 15, quad = lane >> 4;

  __shared__ _Float16 Kbuf[2][8 * 512];  // 2 x 8 KB, frag-chunk layout
  __shared__ _Float16 Vbuf[2][8 * 512];  // 2 x 8 KB
  __shared__ _Float16 St[4][16 * 40];    // 5 KB, per-wave P [m=16][k=32]

  const size_t RS = (size_t)BATCH * NHEAD * 384;
  const _Float16* base = mixed + (size_t)z * 384;
  const unsigned char* mbase = mask + (size_t)b * S_LEN * S_LEN;
  const float scale = 0.08838834764831845f;  // 1/sqrt(128)

  // ---- Q fragments -> registers (scaled). Wave owns rows qb+16w..+15 ----
  h8 qfrag[4];
  {
    const size_t row = (size_t)(qb + 16 * wave + ln);
#pragma unroll
    for (int kq = 0; kq < 4; kq++) {
      h8 v = *(const h8*)(base + row * RS + 32 * kq + 8 * quad);
#pragma unroll
      for (int j = 0; j < 8; j++) v[j] = (_Float16)((float)v[j] * scale);
      qfrag[kq] = v;
    }
  }

  f32x4 o[8];
#pragma unroll
  for (int nt = 0; nt < 8; nt++) o[nt] = (f32x4){0.f, 0.f, 0.f, 0.f};
  float lpart[4] = {0.f, 0.f, 0.f, 0.f};

  const int ntiles = 2 * qt + 2;  // K-tiles of 32

  // stage tile kt into buffer buf: wave stages K chunks {2w,2w+1} and
  // V chunks {2w,2w+1}; each chunk = 1 KB contiguous (64 lanes x 16 B).
  const size_t zt = (size_t)z * 64;
#define STAGE(kt_, buf_)                                                   \
  {                                                                        \
    const size_t tbk = (zt + (kt_)) * (8 * 512) + lane * 8;                \
    _Pragma("unroll") for (int c = 0; c < 2; c++) {                        \
      const int ch = 2 * wave + c;                                         \
      gload16(KP + tbk + ch * 512, &Kbuf[buf_][ch * 512]);                 \
      gload16(VP + tbk + ch * 512, &Vbuf[buf_][ch * 512]);                 \
    }                                                                      \
  }

  STAGE(0, 0)  // prologue

  for (int kt = 0; kt < ntiles; kt++) {
    const int kb = kt * 32;
    const int cur = kt & 1;
    __syncthreads();  // drains this tile's async loads; frees other buffer

    if (kt + 1 < ntiles) STAGE(kt + 1, cur ^ 1)  // lands during this compute

    // mask bytes (8 per lane)
    unsigned char mreg[4][2];
#pragma unroll
    for (int r = 0; r < 4; r++)
#pragma unroll
      for (int jn = 0; jn < 2; jn++)
        mreg[r][jn] = mbase[(size_t)(qb + 16 * wave + 4 * quad + r) * S_LEN +
                            kb + 16 * jn + ln];

    // ---- QK^T: K frags from LDS chunk layout ----
    f32x4 s[2];
    s[0] = (f32x4){0.f, 0.f, 0.f, 0.f};
    s[1] = (f32x4){0.f, 0.f, 0.f, 0.f};
#pragma unroll
    for (int kq = 0; kq < 4; kq++) {
#pragma unroll
      for (int jn = 0; jn < 2; jn++) {
        h8 bk = *(const h8*)&Kbuf[cur][(jn * 4 + kq) * 512 + lane * 8];
        s[jn] = __builtin_amdgcn_mfma_f32_16x16x32_f16(qfrag[kq], bk, s[jn], 0,
                                                       0, 0);
      }
    }

    // ---- no-max softmax -> wave-private St ----
#pragma unroll
    for (int jn = 0; jn < 2; jn++)
#pragma unroll
      for (int r = 0; r < 4; r++) {
        const int grow = qb + 16 * wave + 4 * quad + r;
        const int gcol = kb + 16 * jn + ln;
        const float sv = ((gcol > grow) || mreg[r][jn]) ? -10000.0f : s[jn][r];
        const float p = __expf(sv);
        lpart[r] += p;
        St[wave][(4 * quad + r) * 40 + 16 * jn + ln] = (_Float16)p;
      }
    __threadfence_block();

    // ---- PV: V frags from LDS chunk layout ----
    {
      h8 ap = *(const h8*)&St[wave][ln * 40 + 8 * quad];
#pragma unroll
      for (int nt = 0; nt < 8; nt++) {
        h8 bv = *(const h8*)&Vbuf[cur][nt * 512 + lane * 8];
        o[nt] = __builtin_amdgcn_mfma_f32_16x16x32_f16(ap, bv, o[nt], 0, 0, 0);
      }
    }
  }
#undef STAGE

  // ---- epilogue: single l reduction, normalize, write fp16 ctx ----
#pragma unroll
  for (int r = 0; r < 4; r++) {
    float l = lpart[r];
#pragma unroll
    for (int off = 8; off >= 1; off >>= 1) l += __shfl_xor(l, off, 16);
    const float inv_l = 1.0f / l;
    const size_t row_g = (size_t)(qb + 16 * wave + 4 * quad + r);
    _Float16* dst = ctx + (row_g * BATCH + b) * HID + h * DHEAD;
#pragma unroll
    for (int nt = 0; nt < 8; nt++)
      dst[16 * nt + ln] = (_Float16)(o[nt][r] * inv_l);
  }
}

__global__ void copy_bias(const float* __restrict__ src,
                          float* __restrict__ dst) {
  int i = blockIdx.x * blockDim.x + threadIdx.x;
  if (i < HID) dst[i] = src[i];
}

extern "C" void kernel_launch(void* const* d_in, const int* in_sizes, int n_in,
                              void* d_out, int out_size, void* d_ws,
                              size_t ws_size, hipStream_t stream) {
  (void)in_sizes;
  (void)n_in;
  const float* hs = (const float*)d_in[0];
  const unsigned char* mask = (const unsigned char*)d_in[1];
  const float* qkv_w = (const float*)d_in[2];
  const float* qkv_b = (const float*)d_in[3];
  const float* proj_w = (const float*)d_in[4];
  const float* proj_b = (const float*)d_in[5];
  float* out = (float*)d_out;

  const size_t M = (size_t)S_LEN * BATCH;
  const size_t mixed_e = M * 3 * HID;            // 25.17M halves
  const size_t qkvwt_e = (size_t)3 * HID * HID;  // 12.58M (>= VP 8.39M)
  const size_t hsh_e = M * HID;                  // 8.39M (== KP 8.39M)
  const size_t projwt_e = (size_t)HID * HID;     // 4.19M
  const size_t ctx_e = M * HID;                  // 8.39M
  const size_t need =
      (mixed_e + qkvwt_e + hsh_e + projwt_e + ctx_e) * sizeof(_Float16);
  if (ws_size < need) return;  // 117.5 MB, proven available

  _Float16* mixed = (_Float16*)d_ws;
  _Float16* qkv_wt = mixed + mixed_e;   // aliased as VP after QKV GEMM
  _Float16* hs_h = qkv_wt + qkvwt_e;    // aliased as KP after QKV GEMM
  _Float16* proj_wt = hs_h + hsh_e;
  _Float16* ctx = proj_wt + projwt_e;
  _Float16* KP = hs_h;
  _Float16* VP = qkv_wt;

  cvt_fp16<<<(int)(hsh_e / 4 / 256), 256, 0, stream>>>(hs, hs_h,
                                                       (int)(hsh_e / 4));
  transpose_cvt<<<dim3(3 * HID / 64, HID / 64), 256, 0, stream>>>(
      qkv_w, qkv_wt, HID, 3 * HID);
  transpose_cvt<<<dim3(HID / 64, HID / 64), 256, 0, stream>>>(
      proj_w, proj_wt, HID, HID);

  gemm_256<true, true><<<dim3(3 * HID / 256, M / 256), 512, 0, stream>>>(
      hs_h, qkv_wt, qkv_b, mixed, (int)M, 3 * HID, HID);

  pack_kv<<<dim3(S_LEN / 32, BATCH * NHEAD), 256, 0, stream>>>(mixed, KP, VP);

  flash_attn_v7<<<dim3(S_LEN / 64, NHEAD, BATCH), 256, 0, stream>>>(
      mixed, KP, VP, mask, ctx);

  gemm_256<false, false><<<dim3(HID / 256, M / 256), 512, 0, stream>>>(
      ctx, proj_wt, nullptr, out, (int)M, HID, HID);

  copy_bias<<<(HID + 255) / 256, 256, 0, stream>>>(proj_b, out + M * HID);
}